// Round 3
// baseline (1315.970 us; speedup 1.0000x reference)
//
#include <hip/hip_runtime.h>
#include <math.h>

#define CC    192
#define WWD   256
#define HWSZ  65536
#define BB    4
#define NHD   6
#define HIDDEN 768
#define RSC   0.1f
#define EPSV  1e-5f

typedef short s8v __attribute__((ext_vector_type(8)));
typedef float f4v __attribute__((ext_vector_type(4)));
#define MFMA16(a,b,c) __builtin_amdgcn_mfma_f32_16x16x32_bf16(a,b,c,0,0,0)

__device__ __forceinline__ float b2f(unsigned short h){
  return __uint_as_float(((unsigned int)h) << 16);
}
__device__ __forceinline__ unsigned short f2b(float f){
  unsigned int u = __float_as_uint(f);
  u += 0x7FFFu + ((u >> 16) & 1u);          // RNE
  return (unsigned short)(u >> 16);
}
__device__ __forceinline__ float wredsum(float v){
  #pragma unroll
  for (int off = 32; off > 0; off >>= 1) v += __shfl_xor(v, off, 64);
  return v;
}
// tanh-form GELU (max err vs erf-form ~3e-4; RSC^2-scaled at output -> <1e-5)
__device__ __forceinline__ float gelu(float g){
  float u = g * (0.7978845608028654f + 0.0356774081363001f * g * g);
  float e = __expf(-2.f * fabsf(u));
  float t = __builtin_copysignf((1.f - e) / (1.f + e), u);
  return 0.5f * g * (1.f + t);
}

// ---------------- K0: fp32 -> bf16 weight conversion (all 4 in one) ---------
__global__ __launch_bounds__(256) void k0_all(
    const float* __restrict__ s0, const float* __restrict__ s1,
    const float* __restrict__ s2, const float* __restrict__ s3,
    unsigned short* __restrict__ d0, unsigned short* __restrict__ d1,
    unsigned short* __restrict__ d2, unsigned short* __restrict__ d3)
{
  int i = blockIdx.x * 256 + threadIdx.x;       // 110592 quads total
  const float* s; unsigned short* d; int off;
  if (i < 27648)      { s = s0; d = d0; off = 0; }
  else if (i < 36864) { s = s1; d = d1; off = 27648; }
  else if (i < 73728) { s = s2; d = d2; off = 36864; }
  else                { s = s3; d = d3; off = 73728; }
  int j = i - off;
  float4 v = ((const float4*)s)[j];
  ((ushort4*)d)[j] = make_ushort4(f2b(v.x), f2b(v.y), f2b(v.z), f2b(v.w));
}

// ---------------- K1: fused LN1 stats + pooled normalized sums --------------
// 1024 blocks; block = 256 pixels (64 float4 groups); wave sl owns channels
// [sl*48, sl*48+48). Phase1: stats -> mr. Phase2: re-read (L2/L3-hot) and
// accumulate raw pool S[b,c] = sum_hw (x-mean)*rstd via one atomic per
// (block, channel). n1w/n1b applied later in k2.
__global__ __launch_bounds__(256) void k1_fused(
    const float* __restrict__ x, float2* __restrict__ mr,
    float* __restrict__ pool)
{
  __shared__ float red[2048];
  __shared__ float mrs[512];
  const int pg = threadIdx.x & 63;
  const int sl = threadIdx.x >> 6;
  const int G  = blockIdx.x * 64 + pg;
  const int b  = G >> 14;
  const float* xp = x + (size_t)(b * CC) * HWSZ + ((size_t)(G & 16383) << 2);

  float sx=0.f, sy=0.f, sz=0.f, sw=0.f;
  float qx=0.f, qy=0.f, qz=0.f, qw=0.f;
  #pragma unroll 8
  for (int i = 0; i < 48; ++i){
    float4 v = *(const float4*)(xp + (size_t)(sl * 48 + i) * HWSZ);
    sx += v.x; qx += v.x * v.x;
    sy += v.y; qy += v.y * v.y;
    sz += v.z; qz += v.z * v.z;
    sw += v.w; qw += v.w * v.w;
  }
  float* rp = red + threadIdx.x * 8;
  rp[0]=sx; rp[1]=sy; rp[2]=sz; rp[3]=sw;
  rp[4]=qx; rp[5]=qy; rp[6]=qz; rp[7]=qw;
  __syncthreads();
  if (sl == 0){
    #pragma unroll
    for (int s = 1; s < 4; ++s){
      const float* o = red + (s * 64 + pg) * 8;
      sx += o[0]; sy += o[1]; sz += o[2]; sw += o[3];
      qx += o[4]; qy += o[5]; qz += o[6]; qw += o[7];
    }
    const float inv = 1.f / CC;
    float m0 = sx*inv, m1 = sy*inv, m2 = sz*inv, m3 = sw*inv;
    float r0 = rsqrtf(qx*inv - m0*m0 + EPSV);
    float r1 = rsqrtf(qy*inv - m1*m1 + EPSV);
    float r2 = rsqrtf(qz*inv - m2*m2 + EPSV);
    float r3 = rsqrtf(qw*inv - m3*m3 + EPSV);
    float4* mrv = (float4*)mr;
    mrv[G*2]   = make_float4(m0, r0, m1, r1);
    mrv[G*2+1] = make_float4(m2, r2, m3, r3);
    float* ms = mrs + pg * 8;
    ms[0]=m0; ms[1]=r0; ms[2]=m1; ms[3]=r1;
    ms[4]=m2; ms[5]=r2; ms[6]=m3; ms[7]=r3;
  }
  __syncthreads();
  const float* ms = mrs + pg * 8;
  float m0 = ms[0], r0 = ms[1], m1 = ms[2], r1 = ms[3];
  float m2 = ms[4], r2 = ms[5], m3 = ms[6], r3 = ms[7];
  for (int i = 0; i < 48; ++i){
    float4 v = *(const float4*)(xp + (size_t)(sl * 48 + i) * HWSZ);
    float t = (v.x - m0) * r0 + (v.y - m1) * r1
            + (v.z - m2) * r2 + (v.w - m3) * r3;
    t = wredsum(t);
    if (pg == 0) atomicAdd(&pool[b * CC + sl * 48 + i], t);
  }
}

// ---------------- K2: channel-attention MLP (tiny) --------------------------
__global__ __launch_bounds__(256) void k2_camlp(
    const float* __restrict__ pool,
    const float* __restrict__ n1w, const float* __restrict__ n1b,
    const float* __restrict__ w1, const float* __restrict__ w2,
    float* __restrict__ sig)
{
  __shared__ float t[BB * 12];
  int tid = threadIdx.x;
  if (tid < BB * 12){
    int b = tid / 12, r = tid % 12;
    float a = 0.f;
    for (int c = 0; c < CC; ++c)
      a += (n1w[c] * pool[b * CC + c] + 65536.f * n1b[c]) * w1[r * CC + c];
    a *= (1.f / 65536.f);
    t[tid] = fmaxf(a, 0.f);
  }
  __syncthreads();
  for (int i = tid; i < BB * CC; i += 256){
    int b = i / CC, c = i - b * CC;
    float z = 0.f;
    #pragma unroll
    for (int r = 0; r < 12; ++r) z += t[b * 12 + r] * w2[c * 12 + r];
    sig[i] = 1.f / (1.f + __expf(-z));
  }
}

// ---------------- K4: fused ch-scale + window attention + FFN (MFMA) --------
// LDS map (ushorts), total 26624 us = 53248 B -> 3 blocks/CU:
//  Xs  [0,12800)        64x200  : x1 -> ln2 -> attnO -> proj -> ln3
//  Qs  [12800,17408)    64x72   : Q, then per-head P (wave-local rows)
//  Ks  [17408,22016)    64x72
//  VsT [22016,26624)    64x72   (transposed: [e][tok])
//  Hs0 = Qs region      64x72   (ffn hidden chunk, even p)
//  Hs1 = Ks region      64x72   (ffn hidden chunk, odd p)
//  Ov  = Qs region      64x196  (final pre-residual, bf16)
// fp32 residual x1 held in 12 float4 REGISTERS (loops fully unrolled -> no
// scratch; rule: runtime-indexed arrays spill to local memory).
__global__ __launch_bounds__(256, 3) void k4_win(
    const float* __restrict__ x, const float2* __restrict__ mr,
    const float* __restrict__ sig,
    const float* __restrict__ n1w, const float* __restrict__ n1b,
    const float* __restrict__ n2w, const float* __restrict__ n2b,
    const float* __restrict__ n3w, const float* __restrict__ n3b,
    const unsigned short* __restrict__ qw,   // [576][192] bf16
    const unsigned short* __restrict__ pw,   // [192][192] bf16
    const float* __restrict__ projb,
    const float* __restrict__ rpb,
    const unsigned short* __restrict__ f1w,  // [768][192] bf16
    const float* __restrict__ fb1,
    const unsigned short* __restrict__ f2w,  // [192][768] bf16
    const float* __restrict__ fb2,
    float* __restrict__ out)
{
  __shared__ __align__(16) unsigned short lds[26624];
  unsigned short* Xs  = lds;
  unsigned short* Qs  = lds + 12800;
  unsigned short* Ks  = lds + 17408;
  unsigned short* VsT = lds + 22016;
  unsigned short* Hs0 = lds + 12800;
  unsigned short* Hs1 = lds + 17408;
  unsigned short* Ov  = lds + 12800;

  const int tid  = threadIdx.x;
  const int lane = tid & 63;
  const int wv   = tid >> 6;
  const int l15  = lane & 15;
  const int q    = lane >> 4;

  // XCD swizzle: phys%8 ~ XCD; each XCD gets a contiguous chunk of windows.
  int phys = blockIdx.x;
  int blk  = ((phys & 7) << 9) | (phys >> 3);     // bijective for 4096
  int b   = blk >> 10;
  int wh  = (blk >> 5) & 31;
  int ww  = blk & 31;
  size_t base = (size_t)(b * CC) * HWSZ + (size_t)(wh * 8) * WWD + ww * 8;
  int pbase = (b << 16) | ((wh * 8) << 8) | (ww * 8);   // pixel index base

  // ---- fused k3: x1 = LN1(x)*sig*RS + x -> Xs (bf16) + x1v regs ----
  float4 x1v[12];
  #pragma unroll
  for (int kk = 0; kk < 12; ++kk){
    int idx = kk * 256 + tid;            // [0,3072)
    int c   = idx >> 4;
    int t   = idx & 15;
    int row = t >> 1, col0 = (t & 1) * 4;
    float4 xv = *(const float4*)(x + base + (size_t)c * HWSZ + row * WWD + col0);
    int px = pbase + row * 256 + col0;
    float4 mra = *(const float4*)(mr + px);      // m0,r0,m1,r1
    float4 mrb = *(const float4*)(mr + px + 2);  // m2,r2,m3,r3
    float w  = n1w[c], bv = n1b[c];
    float sv = sig[b * CC + c] * RSC;
    int n0 = row * 8 + col0;
    float4 o;
    o.x = ((xv.x - mra.x) * mra.y * w + bv) * sv + xv.x;
    o.y = ((xv.y - mra.z) * mra.w * w + bv) * sv + xv.y;
    o.z = ((xv.z - mrb.x) * mrb.y * w + bv) * sv + xv.z;
    o.w = ((xv.w - mrb.z) * mrb.w * w + bv) * sv + xv.w;
    x1v[kk] = o;
    Xs[(n0    ) * 200 + c] = f2b(o.x);
    Xs[(n0 + 1) * 200 + c] = f2b(o.y);
    Xs[(n0 + 2) * 200 + c] = f2b(o.z);
    Xs[(n0 + 3) * 200 + c] = f2b(o.w);
  }
  __syncthreads();

  // ---- LN2 in place: 16-lane group per row, 4 rows/wave/iter ----
  {
    float wreg[12], breg[12];
    #pragma unroll
    for (int k = 0; k < 12; ++k){
      wreg[k] = n2w[l15 + 16 * k]; breg[k] = n2b[l15 + 16 * k];
    }
    #pragma unroll
    for (int it = 0; it < 4; ++it){
      int n = it * 16 + wv * 4 + q;
      float v[12]; float s = 0.f, ss = 0.f;
      #pragma unroll
      for (int k = 0; k < 12; ++k){
        v[k] = b2f(Xs[n * 200 + l15 + 16 * k]);
        s += v[k]; ss += v[k] * v[k];
      }
      #pragma unroll
      for (int m = 1; m <= 8; m <<= 1){
        s  += __shfl_xor(s,  m, 64);
        ss += __shfl_xor(ss, m, 64);
      }
      float mean = s * (1.f / CC);
      float rstd = rsqrtf(ss * (1.f / CC) - mean * mean + EPSV);
      #pragma unroll
      for (int k = 0; k < 12; ++k)
        Xs[n * 200 + l15 + 16 * k] = f2b((v[k] - mean) * rstd * wreg[k] + breg[k]);
    }
  }
  __syncthreads();

  // ---- attention over 3 head pairs ----
  float oreg[12][4];
  for (int pr = 0; pr < 3; ++pr){
    for (int t3 = 0; t3 < 3; ++t3){
      int t = wv * 3 + t3;
      int sel = t >> 2;            // 0=Q,1=K,2=V
      int s = t & 3;
      const unsigned short* wrow = qw + (size_t)(sel * 192 + pr * 64 + s * 16 + l15) * 192;
      s8v Bf[6];
      #pragma unroll
      for (int k = 0; k < 6; ++k) Bf[k] = *(const s8v*)(wrow + k * 32 + q * 8);
      #pragma unroll
      for (int mt = 0; mt < 4; ++mt){
        f4v acc = {0.f, 0.f, 0.f, 0.f};
        #pragma unroll
        for (int k = 0; k < 6; ++k){
          s8v Af = *(const s8v*)&Xs[(mt * 16 + l15) * 200 + k * 32 + q * 8];
          acc = MFMA16(Af, Bf[k], acc);
        }
        int row0 = mt * 16 + q * 4;
        if (sel == 0){
          #pragma unroll
          for (int r = 0; r < 4; ++r)
            Qs[(row0 + r) * 72 + s * 16 + l15] = f2b(acc[r] * 0.17677669529663689f);
        } else if (sel == 1){
          #pragma unroll
          for (int r = 0; r < 4; ++r)
            Ks[(row0 + r) * 72 + s * 16 + l15] = f2b(acc[r]);
        } else {
          #pragma unroll
          for (int r = 0; r < 4; ++r)
            VsT[(s * 16 + l15) * 72 + row0 + r] = f2b(acc[r]);
        }
      }
    }
    __syncthreads();

    // ---- QK^T for BOTH heads into registers ----
    float sc[2][4][4];                 // [head][keytile][reg]
    {
      const s8v Aq0 = *(const s8v*)&Qs[(wv * 16 + l15) * 72 + q * 8];
      const s8v Aq1 = *(const s8v*)&Qs[(wv * 16 + l15) * 72 + 32 + q * 8];
      #pragma unroll
      for (int nt = 0; nt < 4; ++nt){
        s8v Bk0 = *(const s8v*)&Ks[(nt * 16 + l15) * 72 + q * 8];
        s8v Bk1 = *(const s8v*)&Ks[(nt * 16 + l15) * 72 + 32 + q * 8];
        f4v a0 = {0.f, 0.f, 0.f, 0.f};
        f4v a1 = {0.f, 0.f, 0.f, 0.f};
        a0 = MFMA16(Aq0, Bk0, a0);
        a1 = MFMA16(Aq1, Bk1, a1);
        #pragma unroll
        for (int r = 0; r < 4; ++r){ sc[0][nt][r] = a0[r]; sc[1][nt][r] = a1[r]; }
      }
    }
    // ---- softmax (registers) ----
    #pragma unroll
    for (int hh = 0; hh < 2; ++hh){
      int h = pr * 2 + hh;
      #pragma unroll
      for (int r = 0; r < 4; ++r){
        int rt = wv * 16 + q * 4 + r;
        int i1 = rt >> 3, j1 = rt & 7;
        float mx = -1e30f;
        #pragma unroll
        for (int nt = 0; nt < 4; ++nt){
          int ct = nt * 16 + l15;
          int i2 = ct >> 3, j2 = ct & 7;
          sc[hh][nt][r] += rpb[((i1 - i2 + 7) * 15 + (j1 - j2 + 7)) * NHD + h];
          mx = fmaxf(mx, sc[hh][nt][r]);
        }
        #pragma unroll
        for (int m = 1; m <= 8; m <<= 1) mx = fmaxf(mx, __shfl_xor(mx, m, 64));
        float sm = 0.f;
        #pragma unroll
        for (int nt = 0; nt < 4; ++nt){
          sc[hh][nt][r] = __expf(sc[hh][nt][r] - mx);
          sm += sc[hh][nt][r];
        }
        #pragma unroll
        for (int m = 1; m <= 8; m <<= 1) sm += __shfl_xor(sm, m, 64);
        float invs = 1.f / sm;
        #pragma unroll
        for (int nt = 0; nt < 4; ++nt) sc[hh][nt][r] *= invs;
      }
    }
    // ---- PV per head: stage P through Qs (wave-local rows; no barrier) ----
    #pragma unroll
    for (int hh = 0; hh < 2; ++hh){
      #pragma unroll
      for (int r = 0; r < 4; ++r)
        #pragma unroll
        for (int nt = 0; nt < 4; ++nt)
          Qs[(wv * 16 + q * 4 + r) * 72 + nt * 16 + l15] = f2b(sc[hh][nt][r]);
      #pragma unroll
      for (int vt = 0; vt < 2; ++vt){
        f4v acc = {0.f, 0.f, 0.f, 0.f};
        #pragma unroll
        for (int kst = 0; kst < 2; ++kst){
          s8v Ap = *(const s8v*)&Qs[(wv * 16 + l15) * 72 + kst * 32 + q * 8];
          s8v Bv = *(const s8v*)&VsT[(hh * 32 + vt * 16 + l15) * 72 + kst * 32 + q * 8];
          acc = MFMA16(Ap, Bv, acc);
        }
        int oi = (pr * 2 + hh) * 2 + vt;
        #pragma unroll
        for (int r = 0; r < 4; ++r) oreg[oi][r] = acc[r];
      }
    }
    __syncthreads();     // end of pair: protect Q/K/V for next QKV writes
  }

  // ---- write attention output -> Xs (A-layout) ----
  #pragma unroll
  for (int oi = 0; oi < 12; ++oi){
    int h2 = oi >> 1, vt = oi & 1;
    int col = h2 * 32 + vt * 16 + l15;
    int row0 = wv * 16 + q * 4;
    #pragma unroll
    for (int r = 0; r < 4; ++r)
      Xs[(row0 + r) * 200 + col] = f2b(oreg[oi][r]);
  }
  __syncthreads();

  // ---- proj: wave owns cols [wv*48, wv*48+48) ----
  f4v pa[3][4];
  for (int j = 0; j < 3; ++j){
    int col = wv * 48 + j * 16 + l15;
    const unsigned short* wrow = pw + (size_t)col * 192;
    s8v Bf[6];
    #pragma unroll
    for (int k = 0; k < 6; ++k) Bf[k] = *(const s8v*)(wrow + k * 32 + q * 8);
    float bv = projb[col];
    #pragma unroll
    for (int mt = 0; mt < 4; ++mt){
      f4v acc = {bv, bv, bv, bv};
      #pragma unroll
      for (int k = 0; k < 6; ++k){
        s8v Af = *(const s8v*)&Xs[(mt * 16 + l15) * 200 + k * 32 + q * 8];
        acc = MFMA16(Af, Bf[k], acc);
      }
      pa[j][mt] = acc;
    }
  }
  __syncthreads();
  #pragma unroll
  for (int j = 0; j < 3; ++j)
    for (int mt = 0; mt < 4; ++mt)
      #pragma unroll
      for (int r = 0; r < 4; ++r)
        Xs[(mt * 16 + q * 4 + r) * 200 + wv * 48 + j * 16 + l15] = f2b(pa[j][mt][r]);
  __syncthreads();

  // ---- LN3 in place: 16-lane group per row ----
  {
    float wreg[12], breg[12];
    #pragma unroll
    for (int k = 0; k < 12; ++k){
      wreg[k] = n3w[l15 + 16 * k]; breg[k] = n3b[l15 + 16 * k];
    }
    #pragma unroll
    for (int it = 0; it < 4; ++it){
      int n = it * 16 + wv * 4 + q;
      float v[12]; float s = 0.f, ss = 0.f;
      #pragma unroll
      for (int k = 0; k < 12; ++k){
        v[k] = b2f(Xs[n * 200 + l15 + 16 * k]);
        s += v[k]; ss += v[k] * v[k];
      }
      #pragma unroll
      for (int m = 1; m <= 8; m <<= 1){
        s  += __shfl_xor(s,  m, 64);
        ss += __shfl_xor(ss, m, 64);
      }
      float mean = s * (1.f / CC);
      float rstd = rsqrtf(ss * (1.f / CC) - mean * mean + EPSV);
      #pragma unroll
      for (int k = 0; k < 12; ++k)
        Xs[n * 200 + l15 + 16 * k] = f2b((v[k] - mean) * rstd * wreg[k] + breg[k]);
    }
  }
  __syncthreads();

  // ---- FFN: 12 hidden chunks of 64, double-buffered & software-pipelined --
  f4v facc[3][4];
  #pragma unroll
  for (int j = 0; j < 3; ++j){
    float bv = fb2[wv * 48 + j * 16 + l15];
    #pragma unroll
    for (int mt = 0; mt < 4; ++mt) facc[j][mt] = (f4v){bv, bv, bv, bv};
  }
  for (int p = 0; p < 12; ++p){
    unsigned short* Hw = (p & 1) ? Hs1 : Hs0;
    unsigned short* Hr = (p & 1) ? Hs0 : Hs1;
    // FFN2 for chunk p-1 (reads Hr) -- independent stream vs FFN1 below
    if (p > 0){
      s8v Ha[4][2];
      #pragma unroll
      for (int mt = 0; mt < 4; ++mt){
        Ha[mt][0] = *(const s8v*)&Hr[(mt * 16 + l15) * 72 + q * 8];
        Ha[mt][1] = *(const s8v*)&Hr[(mt * 16 + l15) * 72 + 32 + q * 8];
      }
      #pragma unroll
      for (int j = 0; j < 3; ++j){
        int col = wv * 48 + j * 16 + l15;
        const unsigned short* wrow = f2w + (size_t)col * HIDDEN + (p - 1) * 64;
        s8v Bf0 = *(const s8v*)(wrow + q * 8);
        s8v Bf1 = *(const s8v*)(wrow + 32 + q * 8);
        #pragma unroll
        for (int mt = 0; mt < 4; ++mt){
          f4v acc = facc[j][mt];
          acc = MFMA16(Ha[mt][0], Bf0, acc);
          acc = MFMA16(Ha[mt][1], Bf1, acc);
          facc[j][mt] = acc;
        }
      }
    }
    // FFN1 chunk p -> Hw (wave owns 16 hidden cols)
    {
      int hcol = p * 64 + wv * 16 + l15;
      const unsigned short* wrow = f1w + (size_t)hcol * 192;
      s8v Bf[6];
      #pragma unroll
      for (int k = 0; k < 6; ++k) Bf[k] = *(const s8v*)(wrow + k * 32 + q * 8);
      float bv = fb1[hcol];
      #pragma unroll
      for (int mt = 0; mt < 4; ++mt){
        f4v acc = {bv, bv, bv, bv};
        #pragma unroll
        for (int k = 0; k < 6; ++k){
          s8v Af = *(const s8v*)&Xs[(mt * 16 + l15) * 200 + k * 32 + q * 8];
          acc = MFMA16(Af, Bf[k], acc);
        }
        #pragma unroll
        for (int r = 0; r < 4; ++r)
          Hw[(mt * 16 + q * 4 + r) * 72 + wv * 16 + l15] = f2b(gelu(acc[r]));
      }
    }
    __syncthreads();
  }
  // final FFN2 chunk 11 (from Hs1)
  {
    s8v Ha[4][2];
    #pragma unroll
    for (int mt = 0; mt < 4; ++mt){
      Ha[mt][0] = *(const s8v*)&Hs1[(mt * 16 + l15) * 72 + q * 8];
      Ha[mt][1] = *(const s8v*)&Hs1[(mt * 16 + l15) * 72 + 32 + q * 8];
    }
    #pragma unroll
    for (int j = 0; j < 3; ++j){
      int col = wv * 48 + j * 16 + l15;
      const unsigned short* wrow = f2w + (size_t)col * HIDDEN + 11 * 64;
      s8v Bf0 = *(const s8v*)(wrow + q * 8);
      s8v Bf1 = *(const s8v*)(wrow + 32 + q * 8);
      #pragma unroll
      for (int mt = 0; mt < 4; ++mt){
        f4v acc = facc[j][mt];
        acc = MFMA16(Ha[mt][0], Bf0, acc);
        acc = MFMA16(Ha[mt][1], Bf1, acc);
        facc[j][mt] = acc;
      }
    }
  }
  __syncthreads();

  // ---- epilogue: ov = ln3 + ffn*RS -> Ov (bf16) ----
  #pragma unroll
  for (int j = 0; j < 3; ++j)
    for (int mt = 0; mt < 4; ++mt)
      #pragma unroll
      for (int r = 0; r < 4; ++r){
        int row = mt * 16 + q * 4 + r;
        int col = wv * 48 + j * 16 + l15;
        float lv = b2f(Xs[row * 200 + col]);
        Ov[row * 196 + col] = f2b(lv + facc[j][mt][r] * RSC);
      }
  __syncthreads();

  // ---- final: out = Ov*RS + x1 (fp32 residual from registers) ----
  #pragma unroll
  for (int kk = 0; kk < 12; ++kk){
    int idx = kk * 256 + tid;
    int c   = idx >> 4;
    int t   = idx & 15;
    int row = t >> 1, col0 = (t & 1) * 4;
    size_t gi = base + (size_t)c * HWSZ + row * WWD + col0;
    int n0 = row * 8 + col0;
    float4 o;
    o.x = b2f(Ov[(n0    ) * 196 + c]) * RSC + x1v[kk].x;
    o.y = b2f(Ov[(n0 + 1) * 196 + c]) * RSC + x1v[kk].y;
    o.z = b2f(Ov[(n0 + 2) * 196 + c]) * RSC + x1v[kk].z;
    o.w = b2f(Ov[(n0 + 3) * 196 + c]) * RSC + x1v[kk].w;
    *(float4*)(out + gi) = o;
  }
}

// ---------------- launch ----------------------------------------------------
extern "C" void kernel_launch(void* const* d_in, const int* in_sizes, int n_in,
                              void* d_out, int out_size, void* d_ws, size_t ws_size,
                              hipStream_t stream)
{
  const float* x    = (const float*)d_in[0];
  const float* n1w  = (const float*)d_in[1];
  const float* n1b  = (const float*)d_in[2];
  const float* n2w  = (const float*)d_in[3];
  const float* n2b  = (const float*)d_in[4];
  const float* n3w  = (const float*)d_in[5];
  const float* n3b  = (const float*)d_in[6];
  const float* caw1 = (const float*)d_in[7];
  const float* caw2 = (const float*)d_in[8];
  const float* qkvw = (const float*)d_in[9];
  const float* projw= (const float*)d_in[10];
  const float* projb= (const float*)d_in[11];
  const float* rpb  = (const float*)d_in[12];
  const float* fw1  = (const float*)d_in[13];
  const float* fb1  = (const float*)d_in[14];
  const float* fw2  = (const float*)d_in[15];
  const float* fb2  = (const float*)d_in[16];
  float* out = (float*)d_out;

  float*  pool = (float*)d_ws;                       // 768 f
  float*  sig  = pool + 768;                         // 768 f
  float2* mr   = (float2*)(sig + 768);               // 262144 float2 (2 MB)
  unsigned short* qw  = (unsigned short*)((char*)d_ws + 6144 + 2097152);
  unsigned short* pwb = qw  + 110592;
  unsigned short* f1b = pwb + 36864;
  unsigned short* f2b_ = f1b + 147456;

  k0_all<<<dim3(432), dim3(256), 0, stream>>>(qkvw, projw, fw1, fw2,
                                              qw, pwb, f1b, f2b_);
  hipMemsetAsync(pool, 0, 768 * sizeof(float), stream);
  k1_fused<<<dim3(1024), dim3(256), 0, stream>>>(x, mr, pool);
  k2_camlp<<<dim3(1),    dim3(256), 0, stream>>>(pool, n1w, n1b, caw1, caw2, sig);
  k4_win  <<<dim3(4096), dim3(256), 0, stream>>>(x, mr, sig, n1w, n1b,
                n2w, n2b, n3w, n3b, qw, pwb, projb, rpb, f1b, fb1, f2b_, fb2, out);
}

// Round 4
// 1172.372 us; speedup vs baseline: 1.1225x; 1.1225x over previous
//
#include <hip/hip_runtime.h>
#include <math.h>

#define CC    192
#define WWD   256
#define HWSZ  65536
#define BB    4
#define NHD   6
#define HIDDEN 768
#define RSC   0.1f
#define EPSV  1e-5f

typedef short s8v __attribute__((ext_vector_type(8)));
typedef float f4v __attribute__((ext_vector_type(4)));
#define MFMA16(a,b,c) __builtin_amdgcn_mfma_f32_16x16x32_bf16(a,b,c,0,0,0)

__device__ __forceinline__ float b2f(unsigned short h){
  return __uint_as_float(((unsigned int)h) << 16);
}
__device__ __forceinline__ unsigned short f2b(float f){
  unsigned int u = __float_as_uint(f);
  u += 0x7FFFu + ((u >> 16) & 1u);          // RNE
  return (unsigned short)(u >> 16);
}
__device__ __forceinline__ float wredsum(float v){
  #pragma unroll
  for (int off = 32; off > 0; off >>= 1) v += __shfl_xor(v, off, 64);
  return v;
}

// ---------------- K0: fp32 -> bf16 weight conversion (all 4 in one) ---------
__global__ __launch_bounds__(256) void k0_all(
    const float* __restrict__ s0, const float* __restrict__ s1,
    const float* __restrict__ s2, const float* __restrict__ s3,
    unsigned short* __restrict__ d0, unsigned short* __restrict__ d1,
    unsigned short* __restrict__ d2, unsigned short* __restrict__ d3)
{
  int i = blockIdx.x * 256 + threadIdx.x;       // 110592 quads total
  const float* s; unsigned short* d; int off;
  if (i < 27648)      { s = s0; d = d0; off = 0; }
  else if (i < 36864) { s = s1; d = d1; off = 27648; }
  else if (i < 73728) { s = s2; d = d2; off = 36864; }
  else                { s = s3; d = d3; off = 73728; }
  int j = i - off;
  float4 v = ((const float4*)s)[j];
  ((ushort4*)d)[j] = make_ushort4(f2b(v.x), f2b(v.y), f2b(v.z), f2b(v.w));
}

// ---------------- K1a: per-pixel LN1 mean/rstd ------------------------------
// 1024 blocks; block covers 256 pixels (64 float4 groups); wave w handles
// channels [w*48, w*48+48); LDS reduce across the 4 waves.
__global__ __launch_bounds__(256) void k1a_stats(
    const float* __restrict__ x, float2* __restrict__ mr)
{
  __shared__ float red[2048];
  const int pg = threadIdx.x & 63;            // float4 group within block
  const int sl = threadIdx.x >> 6;            // channel slice == wave
  const int G  = blockIdx.x * 64 + pg;        // global float4 group
  const int b  = G >> 14;                     // 16384 groups per batch
  const float* xp = x + (size_t)(b * CC) * HWSZ + ((size_t)(G & 16383) << 2);

  float sx=0.f, sy=0.f, sz=0.f, sw=0.f;
  float qx=0.f, qy=0.f, qz=0.f, qw=0.f;
  #pragma unroll 4
  for (int i = 0; i < 48; ++i){
    float4 v = *(const float4*)(xp + (size_t)(sl * 48 + i) * HWSZ);
    sx += v.x; qx += v.x * v.x;
    sy += v.y; qy += v.y * v.y;
    sz += v.z; qz += v.z * v.z;
    sw += v.w; qw += v.w * v.w;
  }
  float* rp = red + threadIdx.x * 8;
  rp[0]=sx; rp[1]=sy; rp[2]=sz; rp[3]=sw;
  rp[4]=qx; rp[5]=qy; rp[6]=qz; rp[7]=qw;
  __syncthreads();
  if (sl == 0){
    #pragma unroll
    for (int s = 1; s < 4; ++s){
      const float* o = red + (s * 64 + pg) * 8;
      sx += o[0]; sy += o[1]; sz += o[2]; sw += o[3];
      qx += o[4]; qy += o[5]; qz += o[6]; qw += o[7];
    }
    const float inv = 1.f / CC;
    float m0 = sx*inv, m1 = sy*inv, m2 = sz*inv, m3 = sw*inv;
    float4* mrv = (float4*)mr;
    mrv[G*2]   = make_float4(m0, rsqrtf(qx*inv - m0*m0 + EPSV),
                             m1, rsqrtf(qy*inv - m1*m1 + EPSV));
    mrv[G*2+1] = make_float4(m2, rsqrtf(qz*inv - m2*m2 + EPSV),
                             m3, rsqrtf(qw*inv - m3*m3 + EPSV));
  }
}

// ---------------- K1b: pooled normalized sums, one block per (b,c) ----------
// pool[b,c] = n1w[c] * sum_hw((x-mean)*rstd) + 65536 * n1b[c]
__global__ __launch_bounds__(256) void k1b_pool(
    const float* __restrict__ x, const float4* __restrict__ mrv,
    const float* __restrict__ n1w, const float* __restrict__ n1b,
    float* __restrict__ pool)
{
  int phys = blockIdx.x;
  int b = phys & 3, c = phys >> 2;     // same-b blocks share an XCD (mod-8 ~ mod-4)
  const float4* xp = (const float4*)(x + (size_t)(b * CC + c) * HWSZ);
  const float4* mp = mrv + (size_t)b * 32768;
  float acc = 0.f;
  for (int g = threadIdx.x; g < 16384; g += 256){
    float4 v   = xp[g];
    float4 m01 = mp[2*g], m23 = mp[2*g+1];
    acc += (v.x - m01.x) * m01.y + (v.y - m01.z) * m01.w
         + (v.z - m23.x) * m23.y + (v.w - m23.z) * m23.w;
  }
  acc = wredsum(acc);
  __shared__ float r4[4];
  if ((threadIdx.x & 63) == 0) r4[threadIdx.x >> 6] = acc;
  __syncthreads();
  if (threadIdx.x == 0)
    pool[b * CC + c] = n1w[c] * (r4[0] + r4[1] + r4[2] + r4[3])
                       + 65536.f * n1b[c];
}

// ---------------- K2: channel-attention MLP (tiny) --------------------------
__global__ __launch_bounds__(256) void k2_camlp(
    const float* __restrict__ pool, const float* __restrict__ w1,
    const float* __restrict__ w2, float* __restrict__ sig)
{
  __shared__ float t[BB * 12];
  int tid = threadIdx.x;
  if (tid < BB * 12){
    int b = tid / 12, r = tid % 12;
    float a = 0.f;
    for (int c = 0; c < CC; ++c) a += pool[b * CC + c] * w1[r * CC + c];
    a *= (1.f / 65536.f);
    t[tid] = fmaxf(a, 0.f);
  }
  __syncthreads();
  for (int i = tid; i < BB * CC; i += 256){
    int b = i / CC, c = i - b * CC;
    float z = 0.f;
    #pragma unroll
    for (int r = 0; r < 12; ++r) z += t[b * 12 + r] * w2[c * 12 + r];
    sig[i] = 1.f / (1.f + __expf(-z));
  }
}

// ---------------- K4: fused ch-scale + window attention + FFN (MFMA) --------
// LDS map (ushorts), total 26624 us = 53248 B -> 3 blocks/CU (LDS-capped).
//  Xs  [0,12800)        64x200  : x1 -> ln2 -> attnO -> proj -> ln3
//  Qs  [12800,17408)    64x72   : Q, then per-head P (wave-local rows)
//  Ks  [17408,22016)    64x72
//  VsT [22016,26624)    64x72   (transposed: [e][tok])
//  Hs  = Qs region      64x136  (ffn hidden chunk)
//  Ov  = Qs region      64x196  (final pre-residual, bf16)
// amdgpu_waves_per_eu(3,3): occupancy is LDS-capped at 3 waves/EU anyway, so
// clamp the allocator's occupancy target -> ~168 VGPR budget -> x1v[12]
// (fp32 residual, fully-unrolled static indexing) stays in REGISTERS, no
// scratch round-trip (round-3 counter evidence: VGPR=84=512/6 -> compiler
// targeted 6 waves/EU and spilled 400MB to scratch).
__global__ void __launch_bounds__(256)
__attribute__((amdgpu_waves_per_eu(3, 3)))
k4_win(
    const float* __restrict__ x, const float2* __restrict__ mr,
    const float* __restrict__ sig,
    const float* __restrict__ n1w, const float* __restrict__ n1b,
    const float* __restrict__ n2w, const float* __restrict__ n2b,
    const float* __restrict__ n3w, const float* __restrict__ n3b,
    const unsigned short* __restrict__ qw,   // [576][192] bf16
    const unsigned short* __restrict__ pw,   // [192][192] bf16
    const float* __restrict__ projb,
    const float* __restrict__ rpb,
    const unsigned short* __restrict__ f1w,  // [768][192] bf16
    const float* __restrict__ fb1,
    const unsigned short* __restrict__ f2w,  // [192][768] bf16
    const float* __restrict__ fb2,
    float* __restrict__ out)
{
  __shared__ __align__(16) unsigned short lds[26624];
  unsigned short* Xs  = lds;
  unsigned short* Qs  = lds + 12800;
  unsigned short* Ks  = lds + 17408;
  unsigned short* VsT = lds + 22016;
  unsigned short* Hs  = lds + 12800;
  unsigned short* Ov  = lds + 12800;

  const int tid  = threadIdx.x;
  const int lane = tid & 63;
  const int wv   = tid >> 6;
  const int l15  = lane & 15;
  const int q    = lane >> 4;

  // XCD swizzle: phys%8 ~ XCD; each XCD gets a contiguous chunk of windows.
  int phys = blockIdx.x;
  int blk  = ((phys & 7) << 9) | (phys >> 3);     // bijective for 4096
  int b   = blk >> 10;
  int wh  = (blk >> 5) & 31;
  int ww  = blk & 31;
  size_t base = (size_t)(b * CC) * HWSZ + (size_t)(wh * 8) * WWD + ww * 8;
  int pbase = (b << 16) | ((wh * 8) << 8) | (ww * 8);   // pixel index base

  // ---- fused k3: x1 = LN1(x)*sig*RS + x -> Xs (bf16) + x1v regs ----
  float4 x1v[12];
  #pragma unroll
  for (int kk = 0; kk < 12; ++kk){
    int idx = kk * 256 + tid;            // [0,3072)
    int c   = idx >> 4;
    int t   = idx & 15;
    int row = t >> 1, col0 = (t & 1) * 4;
    float4 xv = *(const float4*)(x + base + (size_t)c * HWSZ + row * WWD + col0);
    int px = pbase + row * 256 + col0;
    float4 mra = *(const float4*)(mr + px);      // m0,r0,m1,r1
    float4 mrb = *(const float4*)(mr + px + 2);  // m2,r2,m3,r3
    float w  = n1w[c], bv = n1b[c];
    float sv = sig[b * CC + c] * RSC;
    int n0 = row * 8 + col0;
    float4 o;
    o.x = ((xv.x - mra.x) * mra.y * w + bv) * sv + xv.x;
    o.y = ((xv.y - mra.z) * mra.w * w + bv) * sv + xv.y;
    o.z = ((xv.z - mrb.x) * mrb.y * w + bv) * sv + xv.z;
    o.w = ((xv.w - mrb.z) * mrb.w * w + bv) * sv + xv.w;
    x1v[kk] = o;
    Xs[(n0    ) * 200 + c] = f2b(o.x);
    Xs[(n0 + 1) * 200 + c] = f2b(o.y);
    Xs[(n0 + 2) * 200 + c] = f2b(o.z);
    Xs[(n0 + 3) * 200 + c] = f2b(o.w);
  }
  __syncthreads();

  // ---- LN2 in place ----
  {
    float wa = n2w[lane], wb = n2w[lane + 64], wc = n2w[lane + 128];
    float ba = n2b[lane], bb3 = n2b[lane + 64], bc = n2b[lane + 128];
    for (int n = wv; n < 64; n += 4){
      float v0 = b2f(Xs[n * 200 + lane]);
      float v1 = b2f(Xs[n * 200 + lane + 64]);
      float v2 = b2f(Xs[n * 200 + lane + 128]);
      float s  = wredsum(v0 + v1 + v2);
      float ss = wredsum(v0 * v0 + v1 * v1 + v2 * v2);
      float mean = s * (1.f / CC);
      float rstd = rsqrtf(ss * (1.f / CC) - mean * mean + EPSV);
      Xs[n * 200 + lane]       = f2b((v0 - mean) * rstd * wa + ba);
      Xs[n * 200 + lane + 64]  = f2b((v1 - mean) * rstd * wb + bb3);
      Xs[n * 200 + lane + 128] = f2b((v2 - mean) * rstd * wc + bc);
    }
  }
  __syncthreads();

  // ---- attention over 3 head pairs ----
  float oreg[12][4];
  for (int pr = 0; pr < 3; ++pr){
    for (int t3 = 0; t3 < 3; ++t3){
      int t = wv * 3 + t3;
      int sel = t >> 2;            // 0=Q,1=K,2=V
      int s = t & 3;
      const unsigned short* wrow = qw + (size_t)(sel * 192 + pr * 64 + s * 16 + l15) * 192;
      s8v Bf[6];
      #pragma unroll
      for (int k = 0; k < 6; ++k) Bf[k] = *(const s8v*)(wrow + k * 32 + q * 8);
      #pragma unroll
      for (int mt = 0; mt < 4; ++mt){
        f4v acc = {0.f, 0.f, 0.f, 0.f};
        #pragma unroll
        for (int k = 0; k < 6; ++k){
          s8v Af = *(const s8v*)&Xs[(mt * 16 + l15) * 200 + k * 32 + q * 8];
          acc = MFMA16(Af, Bf[k], acc);
        }
        int row0 = mt * 16 + q * 4;
        if (sel == 0){
          #pragma unroll
          for (int r = 0; r < 4; ++r)
            Qs[(row0 + r) * 72 + s * 16 + l15] = f2b(acc[r] * 0.17677669529663689f);
        } else if (sel == 1){
          #pragma unroll
          for (int r = 0; r < 4; ++r)
            Ks[(row0 + r) * 72 + s * 16 + l15] = f2b(acc[r]);
        } else {
          #pragma unroll
          for (int r = 0; r < 4; ++r)
            VsT[(s * 16 + l15) * 72 + row0 + r] = f2b(acc[r]);
        }
      }
    }
    __syncthreads();

    // ---- QK^T for BOTH heads into registers ----
    float sc[2][4][4];                 // [head][keytile][reg]
    {
      const s8v Aq0 = *(const s8v*)&Qs[(wv * 16 + l15) * 72 + q * 8];
      const s8v Aq1 = *(const s8v*)&Qs[(wv * 16 + l15) * 72 + 32 + q * 8];
      #pragma unroll
      for (int nt = 0; nt < 4; ++nt){
        s8v Bk0 = *(const s8v*)&Ks[(nt * 16 + l15) * 72 + q * 8];
        s8v Bk1 = *(const s8v*)&Ks[(nt * 16 + l15) * 72 + 32 + q * 8];
        f4v a0 = {0.f, 0.f, 0.f, 0.f};
        f4v a1 = {0.f, 0.f, 0.f, 0.f};
        a0 = MFMA16(Aq0, Bk0, a0);
        a1 = MFMA16(Aq1, Bk1, a1);
        #pragma unroll
        for (int r = 0; r < 4; ++r){ sc[0][nt][r] = a0[r]; sc[1][nt][r] = a1[r]; }
      }
    }
    // ---- softmax (registers) ----
    #pragma unroll
    for (int hh = 0; hh < 2; ++hh){
      int h = pr * 2 + hh;
      #pragma unroll
      for (int r = 0; r < 4; ++r){
        int rt = wv * 16 + q * 4 + r;
        int i1 = rt >> 3, j1 = rt & 7;
        float mx = -1e30f;
        #pragma unroll
        for (int nt = 0; nt < 4; ++nt){
          int ct = nt * 16 + l15;
          int i2 = ct >> 3, j2 = ct & 7;
          sc[hh][nt][r] += rpb[((i1 - i2 + 7) * 15 + (j1 - j2 + 7)) * NHD + h];
          mx = fmaxf(mx, sc[hh][nt][r]);
        }
        #pragma unroll
        for (int m = 1; m <= 8; m <<= 1) mx = fmaxf(mx, __shfl_xor(mx, m, 64));
        float sm = 0.f;
        #pragma unroll
        for (int nt = 0; nt < 4; ++nt){
          sc[hh][nt][r] = __expf(sc[hh][nt][r] - mx);
          sm += sc[hh][nt][r];
        }
        #pragma unroll
        for (int m = 1; m <= 8; m <<= 1) sm += __shfl_xor(sm, m, 64);
        float invs = 1.f / sm;
        #pragma unroll
        for (int nt = 0; nt < 4; ++nt) sc[hh][nt][r] *= invs;
      }
    }
    // ---- PV per head: stage P through Qs (wave-local rows; no barrier) ----
    #pragma unroll
    for (int hh = 0; hh < 2; ++hh){
      #pragma unroll
      for (int r = 0; r < 4; ++r)
        #pragma unroll
        for (int nt = 0; nt < 4; ++nt)
          Qs[(wv * 16 + q * 4 + r) * 72 + nt * 16 + l15] = f2b(sc[hh][nt][r]);
      #pragma unroll
      for (int vt = 0; vt < 2; ++vt){
        f4v acc = {0.f, 0.f, 0.f, 0.f};
        #pragma unroll
        for (int kst = 0; kst < 2; ++kst){
          s8v Ap = *(const s8v*)&Qs[(wv * 16 + l15) * 72 + kst * 32 + q * 8];
          s8v Bv = *(const s8v*)&VsT[(hh * 32 + vt * 16 + l15) * 72 + kst * 32 + q * 8];
          acc = MFMA16(Ap, Bv, acc);
        }
        int oi = (pr * 2 + hh) * 2 + vt;
        #pragma unroll
        for (int r = 0; r < 4; ++r) oreg[oi][r] = acc[r];
      }
    }
    __syncthreads();     // end of pair: protect Q/K/V for next QKV writes
  }

  // ---- write attention output -> Xs (A-layout) ----
  #pragma unroll
  for (int oi = 0; oi < 12; ++oi){
    int h2 = oi >> 1, vt = oi & 1;
    int col = h2 * 32 + vt * 16 + l15;
    int row0 = wv * 16 + q * 4;
    #pragma unroll
    for (int r = 0; r < 4; ++r)
      Xs[(row0 + r) * 200 + col] = f2b(oreg[oi][r]);
  }
  __syncthreads();

  // ---- proj: wave owns cols [wv*48, wv*48+48) ----
  f4v pa[3][4];
  for (int j = 0; j < 3; ++j){
    int col = wv * 48 + j * 16 + l15;
    const unsigned short* wrow = pw + (size_t)col * 192;
    s8v Bf[6];
    #pragma unroll
    for (int k = 0; k < 6; ++k) Bf[k] = *(const s8v*)(wrow + k * 32 + q * 8);
    float bv = projb[col];
    #pragma unroll
    for (int mt = 0; mt < 4; ++mt){
      f4v acc = {bv, bv, bv, bv};
      #pragma unroll
      for (int k = 0; k < 6; ++k){
        s8v Af = *(const s8v*)&Xs[(mt * 16 + l15) * 200 + k * 32 + q * 8];
        acc = MFMA16(Af, Bf[k], acc);
      }
      pa[j][mt] = acc;
    }
  }
  __syncthreads();
  #pragma unroll
  for (int j = 0; j < 3; ++j)
    for (int mt = 0; mt < 4; ++mt)
      #pragma unroll
      for (int r = 0; r < 4; ++r)
        Xs[(mt * 16 + q * 4 + r) * 200 + wv * 48 + j * 16 + l15] = f2b(pa[j][mt][r]);
  __syncthreads();

  // ---- LN3 in place ----
  {
    float wa = n3w[lane], wb = n3w[lane + 64], wc = n3w[lane + 128];
    float ba = n3b[lane], bb3 = n3b[lane + 64], bc = n3b[lane + 128];
    for (int n = wv; n < 64; n += 4){
      float v0 = b2f(Xs[n * 200 + lane]);
      float v1 = b2f(Xs[n * 200 + lane + 64]);
      float v2 = b2f(Xs[n * 200 + lane + 128]);
      float s  = wredsum(v0 + v1 + v2);
      float ss = wredsum(v0 * v0 + v1 * v1 + v2 * v2);
      float mean = s * (1.f / CC);
      float rstd = rsqrtf(ss * (1.f / CC) - mean * mean + EPSV);
      Xs[n * 200 + lane]       = f2b((v0 - mean) * rstd * wa + ba);
      Xs[n * 200 + lane + 64]  = f2b((v1 - mean) * rstd * wb + bb3);
      Xs[n * 200 + lane + 128] = f2b((v2 - mean) * rstd * wc + bc);
    }
  }
  __syncthreads();

  // ---- FFN: 6 hidden chunks of 128 ----
  f4v facc[3][4];
  #pragma unroll
  for (int j = 0; j < 3; ++j){
    float bv = fb2[wv * 48 + j * 16 + l15];
    #pragma unroll
    for (int mt = 0; mt < 4; ++mt) facc[j][mt] = (f4v){bv, bv, bv, bv};
  }
  for (int hc = 0; hc < 6; ++hc){
    for (int j = 0; j < 2; ++j){
      int hcol = hc * 128 + wv * 32 + j * 16 + l15;
      const unsigned short* wrow = f1w + (size_t)hcol * 192;
      s8v Bf[6];
      #pragma unroll
      for (int k = 0; k < 6; ++k) Bf[k] = *(const s8v*)(wrow + k * 32 + q * 8);
      float bv = fb1[hcol];
      #pragma unroll
      for (int mt = 0; mt < 4; ++mt){
        f4v acc = {bv, bv, bv, bv};
        #pragma unroll
        for (int k = 0; k < 6; ++k){
          s8v Af = *(const s8v*)&Xs[(mt * 16 + l15) * 200 + k * 32 + q * 8];
          acc = MFMA16(Af, Bf[k], acc);
        }
        #pragma unroll
        for (int r = 0; r < 4; ++r){
          float g = acc[r];
          g = 0.5f * g * (1.f + erff(g * 0.70710678118654752f));
          Hs[(mt * 16 + q * 4 + r) * 136 + wv * 32 + j * 16 + l15] = f2b(g);
        }
      }
    }
    __syncthreads();
    for (int j = 0; j < 3; ++j){
      int col = wv * 48 + j * 16 + l15;
      const unsigned short* wrow = f2w + (size_t)col * HIDDEN + hc * 128;
      s8v Bf[4];
      #pragma unroll
      for (int kst = 0; kst < 4; ++kst) Bf[kst] = *(const s8v*)(wrow + kst * 32 + q * 8);
      #pragma unroll
      for (int mt = 0; mt < 4; ++mt){
        f4v acc = facc[j][mt];
        #pragma unroll
        for (int kst = 0; kst < 4; ++kst){
          s8v Af = *(const s8v*)&Hs[(mt * 16 + l15) * 136 + kst * 32 + q * 8];
          acc = MFMA16(Af, Bf[kst], acc);
        }
        facc[j][mt] = acc;
      }
    }
    __syncthreads();
  }

  // ---- epilogue: ov = ln3 + ffn*RS -> Ov (bf16) ----
  #pragma unroll
  for (int j = 0; j < 3; ++j)
    for (int mt = 0; mt < 4; ++mt)
      #pragma unroll
      for (int r = 0; r < 4; ++r){
        int row = mt * 16 + q * 4 + r;
        int col = wv * 48 + j * 16 + l15;
        float lv = b2f(Xs[row * 200 + col]);
        Ov[row * 196 + col] = f2b(lv + facc[j][mt][r] * RSC);
      }
  __syncthreads();

  // ---- final: out = Ov*RS + x1 (fp32 residual from registers) ----
  #pragma unroll
  for (int kk = 0; kk < 12; ++kk){
    int idx = kk * 256 + tid;
    int c   = idx >> 4;
    int t   = idx & 15;
    int row = t >> 1, col0 = (t & 1) * 4;
    size_t gi = base + (size_t)c * HWSZ + row * WWD + col0;
    int n0 = row * 8 + col0;
    float4 o;
    o.x = b2f(Ov[(n0    ) * 196 + c]) * RSC + x1v[kk].x;
    o.y = b2f(Ov[(n0 + 1) * 196 + c]) * RSC + x1v[kk].y;
    o.z = b2f(Ov[(n0 + 2) * 196 + c]) * RSC + x1v[kk].z;
    o.w = b2f(Ov[(n0 + 3) * 196 + c]) * RSC + x1v[kk].w;
    *(float4*)(out + gi) = o;
  }
}

// ---------------- launch ----------------------------------------------------
extern "C" void kernel_launch(void* const* d_in, const int* in_sizes, int n_in,
                              void* d_out, int out_size, void* d_ws, size_t ws_size,
                              hipStream_t stream)
{
  const float* x    = (const float*)d_in[0];
  const float* n1w  = (const float*)d_in[1];
  const float* n1b  = (const float*)d_in[2];
  const float* n2w  = (const float*)d_in[3];
  const float* n2b  = (const float*)d_in[4];
  const float* n3w  = (const float*)d_in[5];
  const float* n3b  = (const float*)d_in[6];
  const float* caw1 = (const float*)d_in[7];
  const float* caw2 = (const float*)d_in[8];
  const float* qkvw = (const float*)d_in[9];
  const float* projw= (const float*)d_in[10];
  const float* projb= (const float*)d_in[11];
  const float* rpb  = (const float*)d_in[12];
  const float* fw1  = (const float*)d_in[13];
  const float* fb1  = (const float*)d_in[14];
  const float* fw2  = (const float*)d_in[15];
  const float* fb2  = (const float*)d_in[16];
  float* out = (float*)d_out;

  float*  pool = (float*)d_ws;                       // 768 f
  float*  sig  = pool + 768;                         // 768 f
  float2* mr   = (float2*)(sig + 768);               // 262144 float2 (2 MB)
  unsigned short* qw  = (unsigned short*)((char*)d_ws + 6144 + 2097152);
  unsigned short* pwb = qw  + 110592;
  unsigned short* f1b = pwb + 36864;
  unsigned short* f2b_ = f1b + 147456;

  k0_all<<<dim3(432), dim3(256), 0, stream>>>(qkvw, projw, fw1, fw2,
                                              qw, pwb, f1b, f2b_);
  k1a_stats<<<dim3(1024), dim3(256), 0, stream>>>(x, mr);
  k1b_pool <<<dim3(768),  dim3(256), 0, stream>>>(x, (const float4*)mr,
                                                  n1w, n1b, pool);
  k2_camlp <<<dim3(1),    dim3(256), 0, stream>>>(pool, caw1, caw2, sig);
  k4_win   <<<dim3(4096), dim3(256), 0, stream>>>(x, mr, sig, n1w, n1b,
                n2w, n2b, n3w, n3b, qw, pwb, projb, rpb, f1b, fb1, f2b_, fb2, out);
}